// Round 3
// baseline (261.643 us; speedup 1.0000x reference)
//
#include <hip/hip_runtime.h>

typedef __bf16 bf8 __attribute__((ext_vector_type(8)));
typedef float f4 __attribute__((ext_vector_type(4)));

// Problem constants (fixed by reference)
constexpr int BSZ = 2, NSEQ = 2048, DIM = 512, NH = 8, DH = 64, INNER = 512;
constexpr int ROWS = BSZ * NSEQ;          // 4096

// Workspace layout (bytes)
constexpr size_t XB_OFF  = 0;                          // x cast bf16: 4096*512*2 = 4 MB
constexpr size_t WQT_OFF = 4194304;                    // W_qkv^T bf16 [1536][512] = 1.5 MB
constexpr size_t WOT_OFF = WQT_OFF + 1572864;          // W_out^T bf16 [512][512] = 0.5 MB
constexpr size_t Q_OFF   = WOT_OFF + 524288;           // Q/8 bf16 [2][8][2048][64] = 4 MB
constexpr size_t K_OFF   = Q_OFF + 4194304;            // K bf16 = 4 MB
constexpr size_t V_OFF   = K_OFF + 4194304;            // V bf16 = 4 MB
constexpr size_t AO_OFF  = V_OFF + 4194304;            // attn out bf16 [4096][512] = 4 MB

// ---------------- prep: cast x to bf16; transpose+cast W_qkv, W_out ----------------
__global__ __launch_bounds__(256) void prep_kernel(
    const float* __restrict__ x, const float* __restrict__ Wq, const float* __restrict__ Wo,
    __bf16* __restrict__ xb, __bf16* __restrict__ wqt, __bf16* __restrict__ wot) {
  int idx = blockIdx.x * 256 + threadIdx.x;
  if (idx < ROWS * DIM) xb[idx] = (__bf16)x[idx];
  if (idx < 3 * INNER * DIM) {            // wqt[n][k] = Wq[k][n],  n<1536, k<512
    int n = idx >> 9, k = idx & 511;
    wqt[idx] = (__bf16)Wq[k * (3 * INNER) + n];
  }
  if (idx < INNER * DIM) {                // wot[n][k] = Wo[k][n]
    int n = idx >> 9, k = idx & 511;
    wot[idx] = (__bf16)Wo[k * DIM + n];
  }
}

// ---------------- kernel 1: qkv = x @ W_qkv, scatter into per-head Q/8, K, V ----------------
__global__ __launch_bounds__(256) void qkv_gemm(
    const __bf16* __restrict__ xb, const __bf16* __restrict__ wqt,
    __bf16* __restrict__ Qh, __bf16* __restrict__ Kh, __bf16* __restrict__ Vh) {
  int bid = blockIdx.x;
  int bn = bid % 24, bm = bid / 24;           // 24 col-tiles of 64, 64 row-tiles of 64
  int lane = threadIdx.x & 63, wid = threadIdx.x >> 6;
  int r0 = bm * 64 + wid * 16;
  const __bf16* ap = xb  + (size_t)(r0 + (lane & 15)) * 512 + ((lane >> 4) * 8);
  const __bf16* bp = wqt + (size_t)(bn * 64 + (lane & 15)) * 512 + ((lane >> 4) * 8);
  f4 acc[4] = {{0.f,0.f,0.f,0.f},{0.f,0.f,0.f,0.f},{0.f,0.f,0.f,0.f},{0.f,0.f,0.f,0.f}};
#pragma unroll
  for (int kk = 0; kk < 16; ++kk) {
    bf8 a = *(const bf8*)(ap + kk * 32);
#pragma unroll
    for (int jt = 0; jt < 4; ++jt) {
      bf8 b = *(const bf8*)(bp + jt * 16 * 512 + kk * 32);
      acc[jt] = __builtin_amdgcn_mfma_f32_16x16x32_bf16(a, b, acc[jt], 0, 0, 0);
    }
  }
#pragma unroll
  for (int jt = 0; jt < 4; ++jt) {
    int col = bn * 64 + jt * 16 + (lane & 15);
    int which = col >> 9;                    // 0=q 1=k 2=v
    int inner = col & 511;
    int h = inner >> 6, d = inner & 63;
    __bf16* dst = which == 0 ? Qh : (which == 1 ? Kh : Vh);
    float scale = which == 0 ? 0.125f : 1.0f;  // fold SCALE=1/8 into Q (exact)
#pragma unroll
    for (int i = 0; i < 4; ++i) {
      int row = r0 + (lane >> 4) * 4 + i;
      int b = row >> 11, n = row & 2047;
      dst[(((size_t)(b * 8 + h)) * 2048 + n) * 64 + d] = (__bf16)(acc[jt][i] * scale);
    }
  }
}

// ---------------- kernel 2: sparsemax attention, 16 q-rows per workgroup ----------------
__global__ __launch_bounds__(1024) void attn_kernel(
    const __bf16* __restrict__ Qh, const __bf16* __restrict__ Kh,
    const __bf16* __restrict__ Vh, __bf16* __restrict__ AO) {
  __shared__ float S[16 * 2048];            // 128 KB, XOR-swizzled rows
  int bid = blockIdx.x;
  int lin = (bid & 7) * 256 + (bid >> 3);   // XCD-aware swizzle (2048 % 8 == 0, bijective)
  int bh = lin >> 7;                        // 0..15 = b*8+h
  int qt = lin & 127;                       // q-tile within head
  int lane = threadIdx.x & 63, wid = threadIdx.x >> 6;   // 16 waves
  int n0 = qt * 16;
  const __bf16* Qp = Qh + ((size_t)bh * 2048 + n0) * 64;
  const __bf16* Kp = Kh + (size_t)bh * 2048 * 64;
  const __bf16* Vp = Vh + (size_t)bh * 2048 * 64;
  int koff = (lane >> 4) * 8;

  // ---- phase 1: S[16][2048] = (Q/8) @ K^T, f32 into LDS ----
  bf8 a0 = *(const bf8*)(Qp + (lane & 15) * 64 + koff);
  bf8 a1 = *(const bf8*)(Qp + (lane & 15) * 64 + 32 + koff);
#pragma unroll
  for (int t = 0; t < 8; ++t) {
    int jt = wid * 8 + t;                   // 128 col-tiles over 16 waves
    const __bf16* kb = Kp + (size_t)(jt * 16 + (lane & 15)) * 64 + koff;
    bf8 b0 = *(const bf8*)(kb);
    bf8 b1 = *(const bf8*)(kb + 32);
    f4 acc = {0.f, 0.f, 0.f, 0.f};
    acc = __builtin_amdgcn_mfma_f32_16x16x32_bf16(a0, b0, acc, 0, 0, 0);
    acc = __builtin_amdgcn_mfma_f32_16x16x32_bf16(a1, b1, acc, 0, 0, 0);
#pragma unroll
    for (int i = 0; i < 4; ++i) {
      int row = (lane >> 4) * 4 + i;        // C layout: col=lane&15, row=(lane>>4)*4+i
      int col = jt * 16 + (lane & 15);
      S[row * 2048 + (col ^ ((row & 7) << 2))] = acc[i];
    }
  }
  __syncthreads();

  // ---- phase 2: one wave per q-row: Michelot sparsemax + sparse gather PV ----
  int row = wid;
  int sw = (row & 7) << 2;
  float z[8][4];
#pragma unroll
  for (int r = 0; r < 8; ++r) {
    int col = r * 256 + lane * 4;
    f4 v = *(const f4*)&S[row * 2048 + (col ^ sw)];
    z[r][0] = v[0]; z[r][1] = v[1]; z[r][2] = v[2]; z[r][3] = v[3];
  }
  // Michelot: tau <- (sum_{z>tau} z - 1)/count, monotone; stop when support stable
  float tau = -1e30f, cprev = -1.0f;
  for (int it = 0; it < 48; ++it) {
    float s = 0.f, c = 0.f;
#pragma unroll
    for (int r = 0; r < 8; ++r)
#pragma unroll
      for (int i = 0; i < 4; ++i) { float zz = z[r][i]; if (zz > tau) { s += zz; c += 1.f; } }
#pragma unroll
    for (int o = 32; o; o >>= 1) { s += __shfl_xor(s, o); c += __shfl_xor(c, o); }
    s = __shfl(s, 0); c = __shfl(c, 0);     // broadcast: all lanes bit-identical
    if (c == cprev) break;
    tau = (s - 1.0f) / c; cprev = c;
  }
  // sparse PV gather: lane = output d
  float acc_o = 0.f;
#pragma unroll
  for (int r = 0; r < 8; ++r) {
#pragma unroll
    for (int i = 0; i < 4; ++i) {
      float p = z[r][i] - tau;
      unsigned long long m = __ballot(p > 0.f);
      while (m) {
        int src = __ffsll((long long)m) - 1;
        m &= m - 1;
        float pj = __shfl(p, src);
        int j = r * 256 + src * 4 + i;
        acc_o += pj * (float)Vp[(size_t)j * 64 + lane];
      }
    }
  }
  int rowg = (bh >> 3) * 2048 + n0 + row;   // [B][N] row
  AO[(size_t)rowg * 512 + (bh & 7) * 64 + lane] = (__bf16)acc_o;
}

// ---------------- kernel 3: out = AO @ W_out + b_out (f32 result) ----------------
__global__ __launch_bounds__(256) void out_gemm(
    const __bf16* __restrict__ A, const __bf16* __restrict__ wot,
    const float* __restrict__ bias, float* __restrict__ out) {
  int bid = blockIdx.x;
  int bn = bid & 7, bm = bid >> 3;          // 8 col-tiles of 64, 64 row-tiles
  int lane = threadIdx.x & 63, wid = threadIdx.x >> 6;
  int r0 = bm * 64 + wid * 16;
  const __bf16* ap = A   + (size_t)(r0 + (lane & 15)) * 512 + ((lane >> 4) * 8);
  const __bf16* bp = wot + (size_t)(bn * 64 + (lane & 15)) * 512 + ((lane >> 4) * 8);
  f4 acc[4] = {{0.f,0.f,0.f,0.f},{0.f,0.f,0.f,0.f},{0.f,0.f,0.f,0.f},{0.f,0.f,0.f,0.f}};
#pragma unroll
  for (int kk = 0; kk < 16; ++kk) {
    bf8 a = *(const bf8*)(ap + kk * 32);
#pragma unroll
    for (int jt = 0; jt < 4; ++jt) {
      bf8 b = *(const bf8*)(bp + jt * 16 * 512 + kk * 32);
      acc[jt] = __builtin_amdgcn_mfma_f32_16x16x32_bf16(a, b, acc[jt], 0, 0, 0);
    }
  }
#pragma unroll
  for (int jt = 0; jt < 4; ++jt) {
    int col = bn * 64 + jt * 16 + (lane & 15);
    float bv = bias[col];
#pragma unroll
    for (int i = 0; i < 4; ++i) {
      int row = r0 + (lane >> 4) * 4 + i;
      out[(size_t)row * 512 + col] = acc[jt][i] + bv;
    }
  }
}

extern "C" void kernel_launch(void* const* d_in, const int* in_sizes, int n_in,
                              void* d_out, int out_size, void* d_ws, size_t ws_size,
                              hipStream_t stream) {
  const float* x  = (const float*)d_in[0];
  const float* Wq = (const float*)d_in[1];
  const float* Wo = (const float*)d_in[2];
  const float* bo = (const float*)d_in[3];
  char* ws = (char*)d_ws;
  __bf16* xb  = (__bf16*)(ws + XB_OFF);
  __bf16* wqt = (__bf16*)(ws + WQT_OFF);
  __bf16* wot = (__bf16*)(ws + WOT_OFF);
  __bf16* Qh  = (__bf16*)(ws + Q_OFF);
  __bf16* Kh  = (__bf16*)(ws + K_OFF);
  __bf16* Vh  = (__bf16*)(ws + V_OFF);
  __bf16* AO  = (__bf16*)(ws + AO_OFF);

  prep_kernel<<<(ROWS * DIM) / 256, 256, 0, stream>>>(x, Wq, Wo, xb, wqt, wot);
  qkv_gemm<<<(ROWS / 64) * (3 * INNER / 64), 256, 0, stream>>>(xb, wqt, Qh, Kh, Vh);
  attn_kernel<<<16 * (NSEQ / 16), 1024, 0, stream>>>(Qh, Kh, Vh, AO);
  out_gemm<<<(ROWS / 64) * (INNER / 64), 256, 0, stream>>>(AO, wot, bo, (float*)d_out);
}

// Round 4
// 222.409 us; speedup vs baseline: 1.1764x; 1.1764x over previous
//
#include <hip/hip_runtime.h>

typedef __bf16 bf8 __attribute__((ext_vector_type(8)));
typedef float f4 __attribute__((ext_vector_type(4)));

// Problem constants (fixed by reference)
constexpr int BSZ = 2, NSEQ = 2048, DIM = 512, NH = 8, DH = 64, INNER = 512;
constexpr int ROWS = BSZ * NSEQ;          // 4096

// Workspace layout (bytes)
constexpr size_t XB_OFF  = 0;                          // x cast bf16: 4096*512*2 = 4 MB
constexpr size_t WQT_OFF = 4194304;                    // W_qkv^T bf16 [1536][512] = 1.5 MB
constexpr size_t WOT_OFF = WQT_OFF + 1572864;          // W_out^T bf16 [512][512] = 0.5 MB
constexpr size_t Q_OFF   = WOT_OFF + 524288;           // Q/8 bf16 [2][8][2048][64] = 4 MB
constexpr size_t K_OFF   = Q_OFF + 4194304;            // K bf16 = 4 MB
constexpr size_t V_OFF   = K_OFF + 4194304;            // V bf16 = 4 MB
constexpr size_t AO_OFF  = V_OFF + 4194304;            // attn out bf16 [4096][512] = 4 MB

// ---------------- prep: cast x to bf16; transpose+cast W_qkv, W_out ----------------
__global__ __launch_bounds__(256) void prep_kernel(
    const float* __restrict__ x, const float* __restrict__ Wq, const float* __restrict__ Wo,
    __bf16* __restrict__ xb, __bf16* __restrict__ wqt, __bf16* __restrict__ wot) {
  int idx = blockIdx.x * 256 + threadIdx.x;
  if (idx < ROWS * DIM) xb[idx] = (__bf16)x[idx];
  if (idx < 3 * INNER * DIM) {            // wqt[n][k] = Wq[k][n],  n<1536, k<512
    int n = idx >> 9, k = idx & 511;
    wqt[idx] = (__bf16)Wq[k * (3 * INNER) + n];
  }
  if (idx < INNER * DIM) {                // wot[n][k] = Wo[k][n]
    int n = idx >> 9, k = idx & 511;
    wot[idx] = (__bf16)Wo[k * DIM + n];
  }
}

// ---------------- kernel 1: qkv = x @ W_qkv, scatter into per-head Q/8, K, V ----------------
__global__ __launch_bounds__(256) void qkv_gemm(
    const __bf16* __restrict__ xb, const __bf16* __restrict__ wqt,
    __bf16* __restrict__ Qh, __bf16* __restrict__ Kh, __bf16* __restrict__ Vh) {
  int bid = blockIdx.x;
  int bn = bid % 24, bm = bid / 24;           // 24 col-tiles of 64, 64 row-tiles of 64
  int lane = threadIdx.x & 63, wid = threadIdx.x >> 6;
  int r0 = bm * 64 + wid * 16;
  const __bf16* ap = xb  + (size_t)(r0 + (lane & 15)) * 512 + ((lane >> 4) * 8);
  const __bf16* bp = wqt + (size_t)(bn * 64 + (lane & 15)) * 512 + ((lane >> 4) * 8);
  f4 acc[4] = {{0.f,0.f,0.f,0.f},{0.f,0.f,0.f,0.f},{0.f,0.f,0.f,0.f},{0.f,0.f,0.f,0.f}};
#pragma unroll
  for (int kk = 0; kk < 16; ++kk) {
    bf8 a = *(const bf8*)(ap + kk * 32);
#pragma unroll
    for (int jt = 0; jt < 4; ++jt) {
      bf8 b = *(const bf8*)(bp + jt * 16 * 512 + kk * 32);
      acc[jt] = __builtin_amdgcn_mfma_f32_16x16x32_bf16(a, b, acc[jt], 0, 0, 0);
    }
  }
#pragma unroll
  for (int jt = 0; jt < 4; ++jt) {
    int col = bn * 64 + jt * 16 + (lane & 15);
    int which = col >> 9;                    // 0=q 1=k 2=v
    int inner = col & 511;
    int h = inner >> 6, d = inner & 63;
    __bf16* dst = which == 0 ? Qh : (which == 1 ? Kh : Vh);
    float scale = which == 0 ? 0.125f : 1.0f;  // fold SCALE=1/8 into Q (exact)
#pragma unroll
    for (int i = 0; i < 4; ++i) {
      int row = r0 + (lane >> 4) * 4 + i;
      int b = row >> 11, n = row & 2047;
      dst[(((size_t)(b * 8 + h)) * 2048 + n) * 64 + d] = (__bf16)(acc[jt][i] * scale);
    }
  }
}

// ---------------- kernel 2: sparsemax attention, 16 q-rows per workgroup ----------------
__global__ __launch_bounds__(1024) void attn_kernel(
    const __bf16* __restrict__ Qh, const __bf16* __restrict__ Kh,
    const __bf16* __restrict__ Vh, __bf16* __restrict__ AO) {
  __shared__ float S[16 * 2048];            // 128 KB, XOR-swizzled rows
  int bid = blockIdx.x;
  int lin = (bid & 7) * 256 + (bid >> 3);   // XCD-aware swizzle (2048 % 8 == 0, bijective)
  int bh = lin >> 7;                        // 0..15 = b*8+h
  int qt = lin & 127;                       // q-tile within head
  int lane = threadIdx.x & 63, wid = threadIdx.x >> 6;   // 16 waves
  int n0 = qt * 16;
  const __bf16* Qp = Qh + ((size_t)bh * 2048 + n0) * 64;
  const __bf16* Kp = Kh + (size_t)bh * 2048 * 64;
  const __bf16* Vp = Vh + (size_t)bh * 2048 * 64;
  int koff = (lane >> 4) * 8;

  // ---- phase 1: S[16][2048] = (Q/8) @ K^T, f32 into LDS ----
  bf8 a0 = *(const bf8*)(Qp + (lane & 15) * 64 + koff);
  bf8 a1 = *(const bf8*)(Qp + (lane & 15) * 64 + 32 + koff);
#pragma unroll
  for (int t = 0; t < 8; ++t) {
    int jt = wid * 8 + t;                   // 128 col-tiles over 16 waves
    const __bf16* kb = Kp + (size_t)(jt * 16 + (lane & 15)) * 64 + koff;
    bf8 b0 = *(const bf8*)(kb);
    bf8 b1 = *(const bf8*)(kb + 32);
    f4 acc = {0.f, 0.f, 0.f, 0.f};
    acc = __builtin_amdgcn_mfma_f32_16x16x32_bf16(a0, b0, acc, 0, 0, 0);
    acc = __builtin_amdgcn_mfma_f32_16x16x32_bf16(a1, b1, acc, 0, 0, 0);
#pragma unroll
    for (int i = 0; i < 4; ++i) {
      int row = (lane >> 4) * 4 + i;        // C layout: col=lane&15, row=(lane>>4)*4+i
      int col = jt * 16 + (lane & 15);
      S[row * 2048 + (col ^ ((row & 7) << 2))] = acc[i];
    }
  }
  __syncthreads();

  // ---- phase 2: one wave per q-row ----
  int row = wid;
  int sw = (row & 7) << 2;
  float z[8][4];
#pragma unroll
  for (int r = 0; r < 8; ++r) {
    int col = r * 256 + lane * 4;
    f4 v = *(const f4*)&S[row * 2048 + (col ^ sw)];
    z[r][0] = v[0]; z[r][1] = v[1]; z[r][2] = v[2]; z[r][3] = v[3];
  }

  // row max (butterfly leaves identical value in all lanes)
  float mx = z[0][0];
#pragma unroll
  for (int r = 0; r < 8; ++r)
#pragma unroll
    for (int i = 0; i < 4; ++i) mx = fmaxf(mx, z[r][i]);
#pragma unroll
  for (int o = 32; o; o >>= 1) mx = fmaxf(mx, __shfl_xor(mx, o));

  // tau* >= max-1, and z <= max-1 implies not in support -> start Michelot at
  // tau0 = max-1 over the (tiny) candidate set only.
  float tau0 = mx - 1.0f;
  float cv0 = 0.f, cv1 = 0.f, cv2 = 0.f, cv3 = 0.f;
  int cj0 = 0, cj1 = 0, cj2 = 0, cj3 = 0, cnt = 0;
#pragma unroll
  for (int r = 0; r < 8; ++r)
#pragma unroll
    for (int i = 0; i < 4; ++i) {
      float zz = z[r][i];
      if (zz > tau0) {
        int col = r * 256 + (lane << 2) + i;
        if (cnt == 0)      { cv0 = zz; cj0 = col; }
        else if (cnt == 1) { cv1 = zz; cj1 = col; }
        else if (cnt == 2) { cv2 = zz; cj2 = col; }
        else if (cnt == 3) { cv3 = zz; cj3 = col; }
        ++cnt;
      }
    }

  float tau = tau0;
  float acc_o = 0.f;
  bool fastpath = (__ballot(cnt > 4) == 0ULL);   // wave-uniform
  if (fastpath) {
    // Michelot on compact candidates
    float cprev = -1.0f;
    for (int it = 0; it < 24; ++it) {
      float s = 0.f, c = 0.f;
      if (cnt > 0 && cv0 > tau) { s += cv0; c += 1.f; }
      if (cnt > 1 && cv1 > tau) { s += cv1; c += 1.f; }
      if (cnt > 2 && cv2 > tau) { s += cv2; c += 1.f; }
      if (cnt > 3 && cv3 > tau) { s += cv3; c += 1.f; }
#pragma unroll
      for (int o = 32; o; o >>= 1) { s += __shfl_xor(s, o); c += __shfl_xor(c, o); }
      if (c == cprev) break;
      tau = (s - 1.0f) / c; cprev = c;
    }
    // sparse PV gather over candidates: lane = output d
#pragma unroll
    for (int k = 0; k < 4; ++k) {
      float pv = k == 0 ? cv0 : (k == 1 ? cv1 : (k == 2 ? cv2 : cv3));
      int   jv = k == 0 ? cj0 : (k == 1 ? cj1 : (k == 2 ? cj2 : cj3));
      float p = (k < cnt) ? pv - tau : 0.f;
      unsigned long long m = __ballot(p > 0.f);
      while (m) {
        int src = __ffsll((long long)m) - 1;
        m &= m - 1;
        float pj = __shfl(p, src);
        int j = __shfl(jv, src);
        acc_o += pj * (float)Vp[(size_t)j * 64 + lane];
      }
    }
  } else {
    // fallback: full-register-scan Michelot from tau0 (rare)
    float cprev = -1.0f;
    for (int it = 0; it < 48; ++it) {
      float s = 0.f, c = 0.f;
#pragma unroll
      for (int r = 0; r < 8; ++r)
#pragma unroll
        for (int i = 0; i < 4; ++i) { float zz = z[r][i]; if (zz > tau) { s += zz; c += 1.f; } }
#pragma unroll
      for (int o = 32; o; o >>= 1) { s += __shfl_xor(s, o); c += __shfl_xor(c, o); }
      if (c == cprev) break;
      tau = (s - 1.0f) / c; cprev = c;
    }
#pragma unroll
    for (int r = 0; r < 8; ++r) {
#pragma unroll
      for (int i = 0; i < 4; ++i) {
        float p = z[r][i] - tau;
        unsigned long long m = __ballot(p > 0.f);
        while (m) {
          int src = __ffsll((long long)m) - 1;
          m &= m - 1;
          float pj = __shfl(p, src);
          int j = r * 256 + src * 4 + i;
          acc_o += pj * (float)Vp[(size_t)j * 64 + lane];
        }
      }
    }
  }
  int rowg = (bh >> 3) * 2048 + n0 + row;   // [B][N] row
  AO[(size_t)rowg * 512 + (bh & 7) * 64 + lane] = (__bf16)acc_o;
}

// ---------------- kernel 3: out = AO @ W_out + b_out (f32 result) ----------------
__global__ __launch_bounds__(256) void out_gemm(
    const __bf16* __restrict__ A, const __bf16* __restrict__ wot,
    const float* __restrict__ bias, float* __restrict__ out) {
  int bid = blockIdx.x;
  int bn = bid & 7, bm = bid >> 3;          // 8 col-tiles of 64, 64 row-tiles
  int lane = threadIdx.x & 63, wid = threadIdx.x >> 6;
  int r0 = bm * 64 + wid * 16;
  const __bf16* ap = A   + (size_t)(r0 + (lane & 15)) * 512 + ((lane >> 4) * 8);
  const __bf16* bp = wot + (size_t)(bn * 64 + (lane & 15)) * 512 + ((lane >> 4) * 8);
  f4 acc[4] = {{0.f,0.f,0.f,0.f},{0.f,0.f,0.f,0.f},{0.f,0.f,0.f,0.f},{0.f,0.f,0.f,0.f}};
#pragma unroll
  for (int kk = 0; kk < 16; ++kk) {
    bf8 a = *(const bf8*)(ap + kk * 32);
#pragma unroll
    for (int jt = 0; jt < 4; ++jt) {
      bf8 b = *(const bf8*)(bp + jt * 16 * 512 + kk * 32);
      acc[jt] = __builtin_amdgcn_mfma_f32_16x16x32_bf16(a, b, acc[jt], 0, 0, 0);
    }
  }
#pragma unroll
  for (int jt = 0; jt < 4; ++jt) {
    int col = bn * 64 + jt * 16 + (lane & 15);
    float bv = bias[col];
#pragma unroll
    for (int i = 0; i < 4; ++i) {
      int row = r0 + (lane >> 4) * 4 + i;
      out[(size_t)row * 512 + col] = acc[jt][i] + bv;
    }
  }
}

extern "C" void kernel_launch(void* const* d_in, const int* in_sizes, int n_in,
                              void* d_out, int out_size, void* d_ws, size_t ws_size,
                              hipStream_t stream) {
  const float* x  = (const float*)d_in[0];
  const float* Wq = (const float*)d_in[1];
  const float* Wo = (const float*)d_in[2];
  const float* bo = (const float*)d_in[3];
  char* ws = (char*)d_ws;
  __bf16* xb  = (__bf16*)(ws + XB_OFF);
  __bf16* wqt = (__bf16*)(ws + WQT_OFF);
  __bf16* wot = (__bf16*)(ws + WOT_OFF);
  __bf16* Qh  = (__bf16*)(ws + Q_OFF);
  __bf16* Kh  = (__bf16*)(ws + K_OFF);
  __bf16* Vh  = (__bf16*)(ws + V_OFF);
  __bf16* AO  = (__bf16*)(ws + AO_OFF);

  prep_kernel<<<(ROWS * DIM) / 256, 256, 0, stream>>>(x, Wq, Wo, xb, wqt, wot);
  qkv_gemm<<<(ROWS / 64) * (3 * INNER / 64), 256, 0, stream>>>(xb, wqt, Qh, Kh, Vh);
  attn_kernel<<<16 * (NSEQ / 16), 1024, 0, stream>>>(Qh, Kh, Vh, AO);
  out_gemm<<<(ROWS / 64) * (INNER / 64), 256, 0, stream>>>(AO, wot, bo, (float*)d_out);
}

// Round 6
// 185.779 us; speedup vs baseline: 1.4084x; 1.1972x over previous
//
#include <hip/hip_runtime.h>

typedef __bf16 bf8 __attribute__((ext_vector_type(8)));
typedef float f4 __attribute__((ext_vector_type(4)));
typedef _Float16 h8 __attribute__((ext_vector_type(8)));

// Problem constants (fixed by reference)
constexpr int BSZ = 2, NSEQ = 2048, DIM = 512, NH = 8, DH = 64, INNER = 512;
constexpr int ROWS = BSZ * NSEQ;          // 4096

// Workspace layout (bytes)
constexpr size_t XB_OFF  = 0;                          // x cast bf16: 4096*512*2 = 4 MB
constexpr size_t WQT_OFF = 4194304;                    // W_qkv^T bf16 [1536][512] = 1.5 MB
constexpr size_t WOT_OFF = WQT_OFF + 1572864;          // W_out^T bf16 [512][512] = 0.5 MB
constexpr size_t Q_OFF   = WOT_OFF + 524288;           // Q/8 bf16 [2][8][2048][64] = 4 MB
constexpr size_t K_OFF   = Q_OFF + 4194304;            // K bf16 = 4 MB
constexpr size_t V_OFF   = K_OFF + 4194304;            // V bf16 = 4 MB
constexpr size_t AO_OFF  = V_OFF + 4194304;            // attn out bf16 [4096][512] = 4 MB

// ---------------- prep: cast x to bf16; transpose+cast W_qkv, W_out ----------------
__global__ __launch_bounds__(256) void prep_kernel(
    const float* __restrict__ x, const float* __restrict__ Wq, const float* __restrict__ Wo,
    __bf16* __restrict__ xb, __bf16* __restrict__ wqt, __bf16* __restrict__ wot) {
  int idx = blockIdx.x * 256 + threadIdx.x;
  if (idx < ROWS * DIM) xb[idx] = (__bf16)x[idx];
  if (idx < 3 * INNER * DIM) {            // wqt[n][k] = Wq[k][n],  n<1536, k<512
    int n = idx >> 9, k = idx & 511;
    wqt[idx] = (__bf16)Wq[k * (3 * INNER) + n];
  }
  if (idx < INNER * DIM) {                // wot[n][k] = Wo[k][n]
    int n = idx >> 9, k = idx & 511;
    wot[idx] = (__bf16)Wo[k * DIM + n];
  }
}

// ---------------- kernel 1: qkv = x @ W_qkv, scatter into per-head Q/8, K, V ----------------
__global__ __launch_bounds__(256) void qkv_gemm(
    const __bf16* __restrict__ xb, const __bf16* __restrict__ wqt,
    __bf16* __restrict__ Qh, __bf16* __restrict__ Kh, __bf16* __restrict__ Vh) {
  int bid = blockIdx.x;
  int bn = bid % 24, bm = bid / 24;           // 24 col-tiles of 64, 64 row-tiles of 64
  int lane = threadIdx.x & 63, wid = threadIdx.x >> 6;
  int r0 = bm * 64 + wid * 16;
  const __bf16* ap = xb  + (size_t)(r0 + (lane & 15)) * 512 + ((lane >> 4) * 8);
  const __bf16* bp = wqt + (size_t)(bn * 64 + (lane & 15)) * 512 + ((lane >> 4) * 8);
  f4 acc[4] = {{0.f,0.f,0.f,0.f},{0.f,0.f,0.f,0.f},{0.f,0.f,0.f,0.f},{0.f,0.f,0.f,0.f}};
#pragma unroll
  for (int kk = 0; kk < 16; ++kk) {
    bf8 a = *(const bf8*)(ap + kk * 32);
#pragma unroll
    for (int jt = 0; jt < 4; ++jt) {
      bf8 b = *(const bf8*)(bp + jt * 16 * 512 + kk * 32);
      acc[jt] = __builtin_amdgcn_mfma_f32_16x16x32_bf16(a, b, acc[jt], 0, 0, 0);
    }
  }
#pragma unroll
  for (int jt = 0; jt < 4; ++jt) {
    int col = bn * 64 + jt * 16 + (lane & 15);
    int which = col >> 9;                    // 0=q 1=k 2=v
    int inner = col & 511;
    int h = inner >> 6, d = inner & 63;
    __bf16* dst = which == 0 ? Qh : (which == 1 ? Kh : Vh);
    float scale = which == 0 ? 0.125f : 1.0f;  // fold SCALE=1/8 into Q (exact)
#pragma unroll
    for (int i = 0; i < 4; ++i) {
      int row = r0 + (lane >> 4) * 4 + i;
      int b = row >> 11, n = row & 2047;
      dst[(((size_t)(b * 8 + h)) * 2048 + n) * 64 + d] = (__bf16)(acc[jt][i] * scale);
    }
  }
}

// ---------------- kernel 2: sparsemax attention, 16 q-rows per workgroup ----------------
// f16 scores (64KB) + 8KB cand lists -> 72KB LDS -> 2 blocks/CU (full 8 waves/SIMD).
__global__ __launch_bounds__(1024, 8) void attn_kernel(
    const __bf16* __restrict__ Qh, const __bf16* __restrict__ Kh,
    const __bf16* __restrict__ Vh, __bf16* __restrict__ AO) {
  __shared__ _Float16 S[16 * 2048];         // 64 KB, XOR-swizzled (col ^= (row&12)<<2)
  __shared__ float candv[16][64];           // 4 KB
  __shared__ int   candj[16][64];           // 4 KB
  int bid = blockIdx.x;
  int lin = (bid & 7) * 256 + (bid >> 3);   // XCD-aware swizzle (2048 % 8 == 0, bijective)
  int bh = lin >> 7;                        // 0..15 = b*8+h
  int qt = lin & 127;                       // q-tile within head
  int lane = threadIdx.x & 63, wid = threadIdx.x >> 6;   // 16 waves
  int n0 = qt * 16;
  const __bf16* Qp = Qh + ((size_t)bh * 2048 + n0) * 64;
  const __bf16* Kp = Kh + (size_t)bh * 2048 * 64;
  const __bf16* Vp = Vh + (size_t)bh * 2048 * 64;
  int koff = (lane >> 4) * 8;

  // ---- phase 1: S[16][2048] = (Q/8) @ K^T, f16 into LDS ----
  bf8 a0 = *(const bf8*)(Qp + (lane & 15) * 64 + koff);
  bf8 a1 = *(const bf8*)(Qp + (lane & 15) * 64 + 32 + koff);
#pragma unroll
  for (int t = 0; t < 8; ++t) {
    int jt = wid * 8 + t;                   // 128 col-tiles over 16 waves
    const __bf16* kb = Kp + (size_t)(jt * 16 + (lane & 15)) * 64 + koff;
    bf8 b0 = *(const bf8*)(kb);
    bf8 b1 = *(const bf8*)(kb + 32);
    f4 acc = {0.f, 0.f, 0.f, 0.f};
    acc = __builtin_amdgcn_mfma_f32_16x16x32_bf16(a0, b0, acc, 0, 0, 0);
    acc = __builtin_amdgcn_mfma_f32_16x16x32_bf16(a1, b1, acc, 0, 0, 0);
#pragma unroll
    for (int i = 0; i < 4; ++i) {
      int row = (lane >> 4) * 4 + i;        // C layout: col=lane&15, row=(lane>>4)*4+i
      int col = jt * 16 + (lane & 15);
      S[row * 2048 + (col ^ ((row & 12) << 2))] = (_Float16)acc[i];
    }
  }
  __syncthreads();

  // ---- phase 2: one wave per q-row ----
  int row = wid;
  int swz = (row & 12) << 2;
  const _Float16* Srow = S + row * 2048;
  h8 zc[4];
#pragma unroll
  for (int r = 0; r < 4; ++r)
    zc[r] = *(const h8*)&Srow[(r * 512 + lane * 8) ^ swz];

  // row max (butterfly leaves identical value in all lanes)
  float mx = -1e30f;
#pragma unroll
  for (int r = 0; r < 4; ++r)
#pragma unroll
    for (int i = 0; i < 8; ++i) mx = fmaxf(mx, (float)zc[r][i]);
#pragma unroll
  for (int o = 32; o; o >>= 1) mx = fmaxf(mx, __shfl_xor(mx, o));

  // tau* >= max-1 (p_max <= 1), so z <= max-1 is provably outside the support.
  float tau0 = mx - 1.0f;
  unsigned mask = 0;
#pragma unroll
  for (int r = 0; r < 4; ++r)
#pragma unroll
    for (int i = 0; i < 8; ++i)
      if ((float)zc[r][i] > tau0) mask |= 1u << (r * 8 + i);
  int pc = __popc(mask);
  int off = pc;                             // inclusive prefix-scan over 64 lanes
#pragma unroll
  for (int d = 1; d < 64; d <<= 1) {
    int t = __shfl_up(off, d);
    if (lane >= d) off += t;
  }
  int total = __shfl(off, 63);              // candidates in this row (wave-uniform)
  off -= pc;                                // exclusive

  float tau = tau0, acc_o = 0.f;
  if (total <= 64) {
    // compact candidates to LDS (wave-private row; no barrier needed)
    int slot = off;
#pragma unroll
    for (int r = 0; r < 4; ++r)
#pragma unroll
      for (int i = 0; i < 8; ++i)
        if (mask & (1u << (r * 8 + i))) {
          candv[row][slot] = (float)zc[r][i];
          candj[row][slot] = r * 512 + lane * 8 + i;
          ++slot;
        }
    // Michelot on 1 candidate per lane
    float v = candv[row][lane];
    bool valid = lane < total;
    float cprev = -1.0f;
    for (int it = 0; it < 24; ++it) {
      bool in = valid && (v > tau);
      float s = in ? v : 0.f, c = in ? 1.f : 0.f;
#pragma unroll
      for (int o = 32; o; o >>= 1) { s += __shfl_xor(s, o); c += __shfl_xor(c, o); }
      if (c == cprev) break;
      tau = (s - 1.0f) / c; cprev = c;
    }
    // uniform gather over compact list: lane = output d, LDS broadcast of (p, j)
    for (int j = 0; j < total; ++j) {
      float p = candv[row][j] - tau;
      if (p > 0.f) {                        // wave-uniform branch
        int idx = candj[row][j];
        acc_o += p * (float)Vp[(size_t)idx * 64 + lane];
      }
    }
  } else {
    // fallback (rare): full-register Michelot from tau0 + ballot gather
    float cprev = -1.0f;
    for (int it = 0; it < 48; ++it) {
      float s = 0.f, c = 0.f;
#pragma unroll
      for (int r = 0; r < 4; ++r)
#pragma unroll
        for (int i = 0; i < 8; ++i) {
          float zz = (float)zc[r][i];
          if (zz > tau) { s += zz; c += 1.f; }
        }
#pragma unroll
      for (int o = 32; o; o >>= 1) { s += __shfl_xor(s, o); c += __shfl_xor(c, o); }
      if (c == cprev) break;
      tau = (s - 1.0f) / c; cprev = c;
    }
#pragma unroll
    for (int r = 0; r < 4; ++r)
#pragma unroll
      for (int i = 0; i < 8; ++i) {
        float p = (float)zc[r][i] - tau;
        unsigned long long m = __ballot(p > 0.f);
        while (m) {
          int src = __ffsll((long long)m) - 1;
          m &= m - 1;
          float pj = __shfl(p, src);
          int j = r * 512 + src * 8 + i;
          acc_o += pj * (float)Vp[(size_t)j * 64 + lane];
        }
      }
  }
  int rowg = (bh >> 3) * 2048 + n0 + row;   // [B][N] row
  AO[(size_t)rowg * 512 + (bh & 7) * 64 + lane] = (__bf16)acc_o;
}

// ---------------- kernel 3: out = AO @ W_out + b_out (f32 result) ----------------
__global__ __launch_bounds__(256) void out_gemm(
    const __bf16* __restrict__ A, const __bf16* __restrict__ wot,
    const float* __restrict__ bias, float* __restrict__ out) {
  int bid = blockIdx.x;
  int bn = bid & 7, bm = bid >> 3;          // 8 col-tiles of 64, 64 row-tiles
  int lane = threadIdx.x & 63, wid = threadIdx.x >> 6;
  int r0 = bm * 64 + wid * 16;
  const __bf16* ap = A   + (size_t)(r0 + (lane & 15)) * 512 + ((lane >> 4) * 8);
  const __bf16* bp = wot + (size_t)(bn * 64 + (lane & 15)) * 512 + ((lane >> 4) * 8);
  f4 acc[4] = {{0.f,0.f,0.f,0.f},{0.f,0.f,0.f,0.f},{0.f,0.f,0.f,0.f},{0.f,0.f,0.f,0.f}};
#pragma unroll
  for (int kk = 0; kk < 16; ++kk) {
    bf8 a = *(const bf8*)(ap + kk * 32);
#pragma unroll
    for (int jt = 0; jt < 4; ++jt) {
      bf8 b = *(const bf8*)(bp + jt * 16 * 512 + kk * 32);
      acc[jt] = __builtin_amdgcn_mfma_f32_16x16x32_bf16(a, b, acc[jt], 0, 0, 0);
    }
  }
#pragma unroll
  for (int jt = 0; jt < 4; ++jt) {
    int col = bn * 64 + jt * 16 + (lane & 15);
    float bv = bias[col];
#pragma unroll
    for (int i = 0; i < 4; ++i) {
      int row = r0 + (lane >> 4) * 4 + i;
      out[(size_t)row * 512 + col] = acc[jt][i] + bv;
    }
  }
}

extern "C" void kernel_launch(void* const* d_in, const int* in_sizes, int n_in,
                              void* d_out, int out_size, void* d_ws, size_t ws_size,
                              hipStream_t stream) {
  const float* x  = (const float*)d_in[0];
  const float* Wq = (const float*)d_in[1];
  const float* Wo = (const float*)d_in[2];
  const float* bo = (const float*)d_in[3];
  char* ws = (char*)d_ws;
  __bf16* xb  = (__bf16*)(ws + XB_OFF);
  __bf16* wqt = (__bf16*)(ws + WQT_OFF);
  __bf16* wot = (__bf16*)(ws + WOT_OFF);
  __bf16* Qh  = (__bf16*)(ws + Q_OFF);
  __bf16* Kh  = (__bf16*)(ws + K_OFF);
  __bf16* Vh  = (__bf16*)(ws + V_OFF);
  __bf16* AO  = (__bf16*)(ws + AO_OFF);

  prep_kernel<<<(ROWS * DIM) / 256, 256, 0, stream>>>(x, Wq, Wo, xb, wqt, wot);
  qkv_gemm<<<(ROWS / 64) * (3 * INNER / 64), 256, 0, stream>>>(xb, wqt, Qh, Kh, Vh);
  attn_kernel<<<16 * (NSEQ / 16), 1024, 0, stream>>>(Qh, Kh, Vh, AO);
  out_gemm<<<(ROWS / 64) * (INNER / 64), 256, 0, stream>>>(AO, wot, bo, (float*)d_out);
}